// Round 1
// baseline (60.322 us; speedup 1.0000x reference)
//
#include <hip/hip_runtime.h>

#define NB 8
#define C_OUT 64
#define NK 11
#define HH 64
#define WW 64
#define NG 4
#define HW (HH*WW)
#define CH (C_OUT*NK)

__global__ __launch_bounds__(256) void fused_addshift_kernel(
    const float* __restrict__ x,
    const int* __restrict__ perm_h,
    const int* __restrict__ perm_v,
    const int* __restrict__ sel_id,
    float* __restrict__ out)
{
    const int blk = blockIdx.x;      // b*C_OUT + r
    const int b = blk >> 6;
    const int r = blk & 63;

    __shared__ float c1[3][NK];
    __shared__ float c2[3][NK];
    __shared__ float cs[NK];
    __shared__ int ic1[3][NK], ic2[3][NK], ics[NK];

    const int tid = threadIdx.x;

    // zero integer histograms
    if (tid < 33) { ic1[tid / 11][tid % 11] = 0; ic2[tid / 11][tid % 11] = 0; }
    if (tid >= 33 && tid < 44) ics[tid - 33] = 0;
    __syncthreads();

    // build count-weights from the permutations (44 (g,k) pairs, 4 sel entries)
    if (tid < 44) {
        int g = tid / 11, k = tid % 11;
        int m = (r * NK + k) % 3;
        int j1 = perm_h[(g * C_OUT + r) * NK + k] % NK;
        int j2 = perm_v[(g * C_OUT + r) * NK + k] % NK;
        atomicAdd(&ic1[m][j1], 1);
        atomicAdd(&ic2[m][j2], 1);
    } else if (tid < 48) {
        int g = tid - 44;
        int j = sel_id[g * C_OUT + r] % NK;
        atomicAdd(&ics[j], 1);
    }
    __syncthreads();
    if (tid < 33) {
        c1[tid / 11][tid % 11] = (float)ic1[tid / 11][tid % 11];
        c2[tid / 11][tid % 11] = (float)ic2[tid / 11][tid % 11];
    }
    if (tid >= 33 && tid < 44) cs[tid - 33] = (float)ics[tid - 33];
    __syncthreads();

    const float* xp = x + ((size_t)b * CH + (size_t)r * NK) * HW;
    float* o1 = out + ((size_t)b * C_OUT + r) * HW;
    float* o2 = o1 + (size_t)NB * C_OUT * HW;
    float* o3 = o2 + (size_t)NB * C_OUT * HW;

    for (int idx = tid; idx < HW; idx += 256) {
        const int h = idx >> 6, w = idx & 63;
        const int hm1 = (h + HH - 1) & (HH - 1);
        const int hm2 = (h + HH - 2) & (HH - 1);
        const int wm1 = (w + WW - 1) & (WW - 1);
        const int wm2 = (w + WW - 2) & (WW - 1);
        const int p0 = h * WW + w;
        const int pA = hm1 * WW + wm2;   // shift (1,2)
        const int pB = hm2 * WW + wm1;   // shift (2,1)
        float l1 = 0.f, l2 = 0.f, sm = 0.f;
        #pragma unroll
        for (int j = 0; j < NK; ++j) {
            const float* cp = xp + j * HW;
            const float X0 = cp[p0];
            const float XA = cp[pA];
            const float XB = cp[pB];
            l1 = fmaf(c1[0][j], X0, fmaf(c1[1][j], XA, fmaf(c1[2][j], XB, l1)));
            l2 = fmaf(c2[0][j], X0, fmaf(c2[1][j], XB, fmaf(c2[2][j], XA, l2)));
            sm = fmaf(cs[j], X0, sm);
        }
        o1[idx] = l1;
        o2[idx] = l2;
        o3[idx] = sm;
    }
}

extern "C" void kernel_launch(void* const* d_in, const int* in_sizes, int n_in,
                              void* d_out, int out_size, void* d_ws, size_t ws_size,
                              hipStream_t stream) {
    const float* x      = (const float*)d_in[0];
    const int* perm_h   = (const int*)d_in[1];
    const int* perm_v   = (const int*)d_in[2];
    const int* sel_id   = (const int*)d_in[3];
    float* out          = (float*)d_out;

    dim3 grid(NB * C_OUT);
    dim3 block(256);
    hipLaunchKernelGGL(fused_addshift_kernel, grid, block, 0, stream,
                       x, perm_h, perm_v, sel_id, out);
}

// Round 2
// 26.183 us; speedup vs baseline: 2.3039x; 2.3039x over previous
//
#include <hip/hip_runtime.h>

#define NB 8
#define C_OUT 64
#define NK 11
#define HH 64
#define WW 64
#define NG 4
#define HW (HH*WW)
#define CH (C_OUT*NK)
#define SPLIT 4          // strips per (b,r) tile; 16 rows each

__global__ __launch_bounds__(256) void fused_addshift_kernel(
    const float* __restrict__ x,
    const int* __restrict__ perm_h,
    const int* __restrict__ perm_v,
    const int* __restrict__ sel_id,
    float* __restrict__ out)
{
    const int blk = blockIdx.x;          // ((b*C_OUT + r) * SPLIT) + strip
    const int strip = blk & (SPLIT - 1);
    const int br = blk >> 2;
    const int b = br >> 6;
    const int r = br & 63;

    __shared__ float c1[3][NK];
    __shared__ float c2[3][NK];
    __shared__ float cs[NK];
    __shared__ int ic1[3][NK], ic2[3][NK], ics[NK];

    const int tid = threadIdx.x;

    if (tid < 33) { ic1[tid / 11][tid % 11] = 0; ic2[tid / 11][tid % 11] = 0; }
    if (tid >= 33 && tid < 44) ics[tid - 33] = 0;
    __syncthreads();

    if (tid < 44) {
        int g = tid / 11, k = tid % 11;
        int m = (r * NK + k) % 3;
        int j1 = perm_h[(g * C_OUT + r) * NK + k] % NK;
        int j2 = perm_v[(g * C_OUT + r) * NK + k] % NK;
        atomicAdd(&ic1[m][j1], 1);
        atomicAdd(&ic2[m][j2], 1);
    } else if (tid < 48) {
        int g = tid - 44;
        int j = sel_id[g * C_OUT + r] % NK;
        atomicAdd(&ics[j], 1);
    }
    __syncthreads();
    if (tid < 33) {
        c1[tid / 11][tid % 11] = (float)ic1[tid / 11][tid % 11];
        c2[tid / 11][tid % 11] = (float)ic2[tid / 11][tid % 11];
    }
    if (tid >= 33 && tid < 44) cs[tid - 33] = (float)ics[tid - 33];
    __syncthreads();

    const float* xp = x + ((size_t)b * CH + (size_t)r * NK) * HW;
    float* o1 = out + ((size_t)b * C_OUT + r) * HW;
    float* o2 = o1 + (size_t)NB * C_OUT * HW;
    float* o3 = o2 + (size_t)NB * C_OUT * HW;

    // thread -> one float4: 16 threads per row, 16 rows per strip
    const int row_local = tid >> 4;            // 0..15
    const int w4 = (tid & 15) << 2;            // 0,4,...,60
    const int h   = strip * 16 + row_local;
    const int hm1 = (h + HH - 1) & (HH - 1);
    const int hm2 = (h + HH - 2) & (HH - 1);
    const int wprev = (w4 + WW - 4) & (WW - 1);

    float4 acc1 = {0.f, 0.f, 0.f, 0.f};
    float4 acc2 = {0.f, 0.f, 0.f, 0.f};
    float4 accs = {0.f, 0.f, 0.f, 0.f};

    #pragma unroll
    for (int j = 0; j < NK; ++j) {
        const float* cp = xp + j * HW;
        const float4 X0 = *reinterpret_cast<const float4*>(cp + h   * WW + w4);
        const float4 a0 = *reinterpret_cast<const float4*>(cp + hm1 * WW + wprev);
        const float4 a1 = *reinterpret_cast<const float4*>(cp + hm1 * WW + w4);
        const float4 b0 = *reinterpret_cast<const float4*>(cp + hm2 * WW + wprev);
        const float4 b1 = *reinterpret_cast<const float4*>(cp + hm2 * WW + w4);

        // XA = row h-1, cols w-2..w+1 ; XB = row h-2, cols w-1..w+2
        const float XAx = a0.z, XAy = a0.w, XAz = a1.x, XAw = a1.y;
        const float XBx = b0.w, XBy = b1.x, XBz = b1.y, XBw = b1.z;

        const float w10 = c1[0][j], w11 = c1[1][j], w12 = c1[2][j];
        const float w20 = c2[0][j], w21 = c2[1][j], w22 = c2[2][j];
        const float wss = cs[j];

        acc1.x = fmaf(w10, X0.x, fmaf(w11, XAx, fmaf(w12, XBx, acc1.x)));
        acc1.y = fmaf(w10, X0.y, fmaf(w11, XAy, fmaf(w12, XBy, acc1.y)));
        acc1.z = fmaf(w10, X0.z, fmaf(w11, XAz, fmaf(w12, XBz, acc1.z)));
        acc1.w = fmaf(w10, X0.w, fmaf(w11, XAw, fmaf(w12, XBw, acc1.w)));

        acc2.x = fmaf(w20, X0.x, fmaf(w21, XBx, fmaf(w22, XAx, acc2.x)));
        acc2.y = fmaf(w20, X0.y, fmaf(w21, XBy, fmaf(w22, XAy, acc2.y)));
        acc2.z = fmaf(w20, X0.z, fmaf(w21, XBz, fmaf(w22, XAz, acc2.z)));
        acc2.w = fmaf(w20, X0.w, fmaf(w21, XBw, fmaf(w22, XAw, acc2.w)));

        accs.x = fmaf(wss, X0.x, accs.x);
        accs.y = fmaf(wss, X0.y, accs.y);
        accs.z = fmaf(wss, X0.z, accs.z);
        accs.w = fmaf(wss, X0.w, accs.w);
    }

    const int idx = h * WW + w4;
    *reinterpret_cast<float4*>(o1 + idx) = acc1;
    *reinterpret_cast<float4*>(o2 + idx) = acc2;
    *reinterpret_cast<float4*>(o3 + idx) = accs;
}

extern "C" void kernel_launch(void* const* d_in, const int* in_sizes, int n_in,
                              void* d_out, int out_size, void* d_ws, size_t ws_size,
                              hipStream_t stream) {
    const float* x      = (const float*)d_in[0];
    const int* perm_h   = (const int*)d_in[1];
    const int* perm_v   = (const int*)d_in[2];
    const int* sel_id   = (const int*)d_in[3];
    float* out          = (float*)d_out;

    dim3 grid(NB * C_OUT * SPLIT);
    dim3 block(256);
    hipLaunchKernelGGL(fused_addshift_kernel, grid, block, 0, stream,
                       x, perm_h, perm_v, sel_id, out);
}